// Round 2
// baseline (2286.779 us; speedup 1.0000x reference)
//
#include <hip/hip_runtime.h>
#include <hip/hip_bf16.h>

// FNO2D: B=8, C=64, H=W=256, MODES=20.
// Spectral conv computed as partial DFTs (only 40x20 modes ever used).
// Layer update done IN-PLACE (speclin blocks own their (b,h) row exclusively),
// so only ONE 134 MB activation buffer is needed -> ws use ~162 MB.

#define NB 8
#define NC 64
#define NH 256
#define NW 256
#define NMODE 20

// ---------------------------------------------------------------- init tables
__global__ __launch_bounds__(256) void init_k(const float* __restrict__ cw,
                                              float* __restrict__ costab, float* __restrict__ sintab,
                                              float* __restrict__ EA, float* __restrict__ Tw,
                                              float* __restrict__ cwT, float* __restrict__ stats) {
    int idx = blockIdx.x * 256 + threadIdx.x;
    const float PH = 6.28318530717958647692f / 256.f;
    if (idx < 256) {
        float s, c; sincosf(idx * PH, &s, &c);
        costab[idx] = c; sintab[idx] = s;
    } else if (idx < 256 + 10240) {            // EA[w][2*ky+p]: forward DFT along W
        int e = idx - 256;
        int w = e / 40, n = e % 40, ky = n >> 1;
        int r = (ky * w) & 255;
        float s, c; sincosf(r * PH, &s, &c);
        EA[e] = (n & 1) ? -s : c;
    } else if (idx < 256 + 20480) {            // Tw[kp][w]: irfft along W (ortho, Im(z0) dropped)
        int e = idx - 10496;
        int kp = e >> 8, w = e & 255;
        int ky = kp >> 1, p = kp & 1;
        int r = (ky * w) & 255;
        float s, c; sincosf(r * PH, &s, &c);
        float v;
        if (ky == 0) v = p ? 0.f : (1.f / 16.f);
        else         v = p ? (-2.f / 16.f) * s : (2.f / 16.f) * c;
        Tw[e] = v;
    } else if (idx < 256 + 20480 + 16384) {    // cwT[l][i][o] = cw[l][o][i]
        int e = idx - 20736;
        int l = e >> 12, r2 = e & 4095;
        int i = r2 >> 6, o = r2 & 63;
        cwT[e] = cw[(l << 12) + (o << 6) + i];
    } else if (idx < 256 + 20480 + 16384 + 512) {
        stats[idx - 37120] = 0.f;              // zero BN-stats accumulators
    }
}

// ------------------------------------------------------------------------ fc0
__global__ __launch_bounds__(256) void fc0_k(const float* __restrict__ x,
                                             const float* __restrict__ w,
                                             const float* __restrict__ bias,
                                             float* __restrict__ outb) {
    __shared__ float ws[768];
    __shared__ float bs[64];
    int tid = threadIdx.x;
    for (int i = tid; i < 768; i += 256) ws[i] = w[i];
    if (tid < 64) bs[tid] = bias[tid];
    __syncthreads();
    int pix = blockIdx.x * 256 + tid;           // 0..524287
    int b = pix >> 16, hw = pix & 65535;
    float xv[12];
#pragma unroll
    for (int t = 0; t < 12; ++t) xv[t] = x[pix * 12 + t];
    int base = (b << 22) + hw;
    for (int c = 0; c < 64; ++c) {
        float a = bs[c];
#pragma unroll
        for (int t = 0; t < 12; ++t) a += xv[t] * ws[t * 64 + c];
        outb[base + (c << 16)] = a;
    }
}

// --------------------------------------------------- stage A: DFT along W (GEMM)
// T[row][2ky+p] = sum_w X[row][w] * EA[w][2ky+p],  rows = (b*64+c)*256+h
__global__ __launch_bounds__(128) void dftw_k(const float* __restrict__ X,
                                              const float* __restrict__ EA,
                                              float* __restrict__ T) {
    __shared__ __align__(16) float Xs[32 * 68];   // transposed [k][m]
    __shared__ float Es[32 * 40];
    int tid = threadIdx.x;
    int tm = tid >> 3, tn = tid & 7;
    int row0 = blockIdx.x << 6;
    float acc[4][5];
#pragma unroll
    for (int i = 0; i < 4; ++i)
#pragma unroll
        for (int j = 0; j < 5; ++j) acc[i][j] = 0.f;

    for (int kc = 0; kc < 256; kc += 32) {
        __syncthreads();
#pragma unroll
        for (int r = 0; r < 4; ++r) {
            int m = tm + (r << 4);
            float4 v = *(const float4*)&X[(row0 + m) * 256 + kc + (tn << 2)];
            int kb = tn << 2;
            Xs[(kb + 0) * 68 + m] = v.x;
            Xs[(kb + 1) * 68 + m] = v.y;
            Xs[(kb + 2) * 68 + m] = v.z;
            Xs[(kb + 3) * 68 + m] = v.w;
        }
        for (int i = tid; i < 1280; i += 128) Es[i] = EA[kc * 40 + i];
        __syncthreads();
#pragma unroll 8
        for (int kk = 0; kk < 32; ++kk) {
            float4 a = *(const float4*)&Xs[kk * 68 + (tm << 2)];
#pragma unroll
            for (int j = 0; j < 5; ++j) {
                float bv = Es[kk * 40 + tn * 5 + j];
                acc[0][j] += a.x * bv;
                acc[1][j] += a.y * bv;
                acc[2][j] += a.z * bv;
                acc[3][j] += a.w * bv;
            }
        }
    }
#pragma unroll
    for (int i = 0; i < 4; ++i) {
        int row = row0 + (tm << 2) + i;
#pragma unroll
        for (int j = 0; j < 5; ++j) T[row * 40 + tn * 5 + j] = acc[i][j];
    }
}

// ------------------------------------------- stage B: DFT along H (256 -> 40 rows)
// XF[b][kx][ky][2c+p], scale 1/256 (full forward ortho)
__global__ __launch_bounds__(256) void dfth_k(const float* __restrict__ T,
                                              const float* __restrict__ ct, const float* __restrict__ st,
                                              float* __restrict__ XF) {
    __shared__ __align__(16) float Ts[10240];
    __shared__ float cts[256], sts[256];
    int tid = threadIdx.x;
    int bc = blockIdx.x;
    for (int i = tid; i < 10240; i += 256) Ts[i] = T[bc * 10240 + i];
    cts[tid] = ct[tid]; sts[tid] = st[tid];
    __syncthreads();
    if (tid < 200) {
        int kxi = tid / 5, kyg = tid % 5;
        int kxa = kxi < 20 ? kxi : kxi + 216;
        float ar0 = 0, ai0 = 0, ar1 = 0, ai1 = 0, ar2 = 0, ai2 = 0, ar3 = 0, ai3 = 0;
        int r = 0;
        for (int h = 0; h < 256; ++h) {
            float cc = cts[r], sv = sts[r];
            r = (r + kxa) & 255;
            float4 v0 = *(const float4*)&Ts[h * 40 + (kyg << 3)];
            float4 v1 = *(const float4*)&Ts[h * 40 + (kyg << 3) + 4];
            ar0 += v0.x * cc + v0.y * sv;  ai0 += v0.y * cc - v0.x * sv;
            ar1 += v0.z * cc + v0.w * sv;  ai1 += v0.w * cc - v0.z * sv;
            ar2 += v1.x * cc + v1.y * sv;  ai2 += v1.y * cc - v1.x * sv;
            ar3 += v1.z * cc + v1.w * sv;  ai3 += v1.w * cc - v1.z * sv;
        }
        int b = bc >> 6, c = bc & 63;
        const float s = 1.f / 256.f;
        int A = (b * 40 + kxi) * 20 + (kyg << 2);
        float2* O = (float2*)XF;
        O[(A + 0) * 64 + c] = make_float2(ar0 * s, ai0 * s);
        O[(A + 1) * 64 + c] = make_float2(ar1 * s, ai1 * s);
        O[(A + 2) * 64 + c] = make_float2(ar2 * s, ai2 * s);
        O[(A + 3) * 64 + c] = make_float2(ar3 * s, ai3 * s);
    }
}

// ---------------------------------------------------------------- mode einsum
// YF[b][x][y][o] = sum_i XF[b][x][y][i] * w[i][o][x'][y]   (w1 for x<20, w2 else)
__global__ __launch_bounds__(512) void eins_k(const float* __restrict__ XF,
                                              const float* __restrict__ w1, const float* __restrict__ w2,
                                              float* __restrict__ YF) {
    __shared__ float xfs[1024];
    int tid = threadIdx.x;
    int x = blockIdx.x / 20, y = blockIdx.x % 20;
    for (int i = tid; i < 1024; i += 512) {
        int b = i >> 7, rr = i & 127;
        xfs[i] = XF[(b * 40 + x) * 2560 + y * 128 + rr];
    }
    __syncthreads();
    int b = tid >> 6, o = tid & 63;
    const float* wp = (x < 20) ? (w1 + (x * 20 + y) * 2) : (w2 + ((x - 20) * 20 + y) * 2);
    float ar = 0.f, ai = 0.f;
#pragma unroll 8
    for (int i = 0; i < 64; ++i) {
        float2 wv = *(const float2*)&wp[(i * 64 + o) * 800];
        float xr = xfs[(b << 7) + (i << 1)];
        float xi = xfs[(b << 7) + (i << 1) + 1];
        ar += xr * wv.x - xi * wv.y;
        ai += xr * wv.y + xi * wv.x;
    }
    ((float2*)YF)[((b * 40 + x) * 20 + y) * 64 + o] = make_float2(ar, ai);
}

// ------------------------------------ stage C: inverse (full complex) DFT along H
// Z[b][co][h][kp], scale 1/16
__global__ __launch_bounds__(256) void idfth_k(const float* __restrict__ YF,
                                               const float* __restrict__ ct, const float* __restrict__ st,
                                               float* __restrict__ Z) {
    __shared__ __align__(16) float yfs[1600];
    __shared__ float cts[256], sts[256];
    int tid = threadIdx.x;
    int bc = blockIdx.x;
    int b = bc >> 6, co = bc & 63;
    for (int i = tid; i < 800; i += 256) {
        int kx = i / 20, ky = i % 20;
        float2 v = ((const float2*)YF)[((b * 40 + kx) * 20 + ky) * 64 + co];
        yfs[kx * 40 + 2 * ky] = v.x;
        yfs[kx * 40 + 2 * ky + 1] = v.y;
    }
    cts[tid] = ct[tid]; sts[tid] = st[tid];
    __syncthreads();
    int h = tid;
    float accr[20], acci[20];
#pragma unroll
    for (int q = 0; q < 20; ++q) { accr[q] = 0.f; acci[q] = 0.f; }
#pragma unroll 2
    for (int kxi = 0; kxi < 40; ++kxi) {
        int kxa = kxi < 20 ? kxi : kxi + 216;
        int r = (kxa * h) & 255;
        float cc = cts[r], sv = sts[r];
#pragma unroll
        for (int q = 0; q < 10; ++q) {
            float4 v = *(const float4*)&yfs[kxi * 40 + (q << 2)];
            accr[2 * q]     += v.x * cc - v.y * sv;  acci[2 * q]     += v.x * sv + v.y * cc;
            accr[2 * q + 1] += v.z * cc - v.w * sv;  acci[2 * q + 1] += v.z * sv + v.w * cc;
        }
    }
    const float s = 1.f / 16.f;
    int base = (bc * 256 + h) * 40;
#pragma unroll
    for (int q = 0; q < 10; ++q) {
        float4 o4;
        o4.x = accr[2 * q] * s;     o4.y = acci[2 * q] * s;
        o4.z = accr[2 * q + 1] * s; o4.w = acci[2 * q + 1] * s;
        *(float4*)&Z[base + (q << 2)] = o4;
    }
}

// ------------------- stage D fused with 1x1 conv + bias + BN-stats accumulation
// pre[b][o][h][w] = sum_i cw[o][i]*hin[b][i][h][w] + sum_kp Z[b][o][h][kp]*Tw[kp][w] + cb[o]
// IN-PLACE SAFE: block (b,h) reads only row (b,:,h,:) of hin (all reads complete
// before any write) and writes only row (b,:,h,:).
__global__ __launch_bounds__(256, 2) void speclin_k(const float* __restrict__ hin,
                                                    const float* __restrict__ Z,
                                                    const float* __restrict__ cwTl,
                                                    const float* __restrict__ TwT,
                                                    const float* __restrict__ cbl,
                                                    float* __restrict__ pre,
                                                    float* __restrict__ statsl) {
    __shared__ __align__(16) float As[104 * 68];
    __shared__ float Bs[26 * 256];
    int tid = threadIdx.x;
    int bh = blockIdx.x;
    int b = bh >> 8, h = bh & 255;
    int to = tid >> 4, tw = tid & 15, o0 = to << 2;

    for (int i = tid; i < 4096; i += 256) { int k = i >> 6, o = i & 63; As[k * 68 + o] = cwTl[i]; }
    for (int i = tid; i < 2560; i += 256) {
        int o = i / 40, kp = i % 40;
        As[(64 + kp) * 68 + o] = Z[((b * 64 + o) * 256 + h) * 40 + kp];
    }
    float acc[4][16];
#pragma unroll
    for (int j = 0; j < 16; ++j) { acc[0][j] = 0.f; acc[1][j] = 0.f; acc[2][j] = 0.f; acc[3][j] = 0.f; }

    for (int ch = 0; ch < 4; ++ch) {
        __syncthreads();
        for (int i = tid; i < 6656; i += 256) {
            int kk = i >> 8, w = i & 255, gk = ch * 26 + kk;
            Bs[i] = (gk < 64) ? hin[((b * 64 + gk) * 256 + h) * 256 + w]
                              : TwT[(gk - 64) * 256 + w];
        }
        __syncthreads();
#pragma unroll 2
        for (int kk = 0; kk < 26; ++kk) {
            int gk = ch * 26 + kk;
            float4 a = *(const float4*)&As[gk * 68 + o0];
#pragma unroll
            for (int j = 0; j < 16; ++j) {
                float bv = Bs[kk * 256 + (j << 4) + tw];
                acc[0][j] += a.x * bv; acc[1][j] += a.y * bv;
                acc[2][j] += a.z * bv; acc[3][j] += a.w * bv;
            }
        }
    }
    float cbv[4];
#pragma unroll
    for (int i = 0; i < 4; ++i) cbv[i] = cbl[o0 + i];
#pragma unroll
    for (int i = 0; i < 4; ++i) {
        float sum = 0.f, sq = 0.f;
        int obase = ((b * 64 + o0 + i) * 256 + h) * 256;
#pragma unroll
        for (int j = 0; j < 16; ++j) {
            float v = acc[i][j] + cbv[i];
            pre[obase + (j << 4) + tw] = v;
            sum += v; sq += v * v;
        }
        sum += __shfl_xor(sum, 1); sq += __shfl_xor(sq, 1);
        sum += __shfl_xor(sum, 2); sq += __shfl_xor(sq, 2);
        sum += __shfl_xor(sum, 4); sq += __shfl_xor(sq, 4);
        sum += __shfl_xor(sum, 8); sq += __shfl_xor(sq, 8);
        if (tw == 0) {
            atomicAdd(&statsl[o0 + i], sum);
            atomicAdd(&statsl[64 + o0 + i], sq);
        }
    }
}

// ----------------------------------------------------------------- BN (+ReLU)
__global__ __launch_bounds__(256) void bn_k(float* __restrict__ buf,
                                            const float* __restrict__ statsl,
                                            const float* __restrict__ g, const float* __restrict__ bta,
                                            int dorelu) {
    int idx4 = blockIdx.x * 256 + threadIdx.x;   // 8,388,608 float4s
    int c = (idx4 >> 14) & 63;
    const float invN = 1.f / 524288.f;
    float mean = statsl[c] * invN;
    float var = statsl[64 + c] * invN - mean * mean;
    float sc = g[c] * rsqrtf(var + 1e-5f);
    float sh = bta[c] - mean * sc;
    float4 v = ((float4*)buf)[idx4];
    v.x = v.x * sc + sh; v.y = v.y * sc + sh; v.z = v.z * sc + sh; v.w = v.w * sc + sh;
    if (dorelu) {
        v.x = fmaxf(v.x, 0.f); v.y = fmaxf(v.y, 0.f);
        v.z = fmaxf(v.z, 0.f); v.w = fmaxf(v.w, 0.f);
    }
    ((float4*)buf)[idx4] = v;
}

// ------------------------------------------------------------ fc1+relu+fc2 fused
__global__ __launch_bounds__(256, 2) void fc12_k(const float* __restrict__ hin,
                                                 const float* __restrict__ w1, const float* __restrict__ b1,
                                                 const float* __restrict__ w2, const float* __restrict__ b2,
                                                 float* __restrict__ out) {
    __shared__ __align__(16) float As[8192];  // fc1_w [64][128]
    __shared__ float Bs[4096];                // k-chunk 16 x 256, reused as reduction scratch
    int tid = threadIdx.x;
    int bh = blockIdx.x;
    int b = bh >> 8, h = bh & 255;
    int to = tid >> 4, tw = tid & 15, d0 = to << 3;

    for (int i = tid; i < 8192; i += 256) As[i] = w1[i];
    float acc[8][16];
#pragma unroll
    for (int j = 0; j < 16; ++j)
#pragma unroll
        for (int i = 0; i < 8; ++i) acc[i][j] = 0.f;

    for (int ch = 0; ch < 4; ++ch) {
        __syncthreads();
        for (int i = tid; i < 4096; i += 256) {
            int kk = i >> 8, w = i & 255;
            Bs[i] = hin[((b * 64 + ch * 16 + kk) * 256 + h) * 256 + w];
        }
        __syncthreads();
#pragma unroll 2
        for (int kk = 0; kk < 16; ++kk) {
            int k = ch * 16 + kk;
            float4 a0 = *(const float4*)&As[k * 128 + d0];
            float4 a1 = *(const float4*)&As[k * 128 + d0 + 4];
#pragma unroll
            for (int j = 0; j < 16; ++j) {
                float bv = Bs[kk * 256 + (j << 4) + tw];
                acc[0][j] += a0.x * bv; acc[1][j] += a0.y * bv;
                acc[2][j] += a0.z * bv; acc[3][j] += a0.w * bv;
                acc[4][j] += a1.x * bv; acc[5][j] += a1.y * bv;
                acc[6][j] += a1.z * bv; acc[7][j] += a1.w * bv;
            }
        }
    }
    float bb[8], wv[8];
#pragma unroll
    for (int i = 0; i < 8; ++i) { bb[i] = b1[d0 + i]; wv[i] = w2[d0 + i]; }
    __syncthreads();   // done reading Bs as data; reuse as reduction scratch
#pragma unroll
    for (int j = 0; j < 16; ++j) {
        float p = 0.f;
#pragma unroll
        for (int i = 0; i < 8; ++i) p += fmaxf(acc[i][j] + bb[i], 0.f) * wv[i];
        Bs[to * 256 + (j << 4) + tw] = p;
    }
    __syncthreads();
    int w = tid;
    float s2 = b2[0];
#pragma unroll
    for (int t2 = 0; t2 < 16; ++t2) s2 += Bs[t2 * 256 + w];
    out[(b * 256 + h) * 256 + w] = s2;
}

// ------------------------------------------------------------------- launcher
extern "C" void kernel_launch(void* const* d_in, const int* in_sizes, int n_in,
                              void* d_out, int out_size, void* d_ws, size_t ws_size,
                              hipStream_t stream) {
    (void)in_sizes; (void)n_in; (void)out_size; (void)ws_size;
    const float* x     = (const float*)d_in[0];
    const float* fc0_w = (const float*)d_in[1];
    const float* fc0_b = (const float*)d_in[2];
    const float* sw1   = (const float*)d_in[3];
    const float* sw2   = (const float*)d_in[4];
    const float* cw    = (const float*)d_in[5];
    const float* cb    = (const float*)d_in[6];
    const float* bng   = (const float*)d_in[7];
    const float* bnb   = (const float*)d_in[8];
    const float* fc1_w = (const float*)d_in[9];
    const float* fc1_b = (const float*)d_in[10];
    const float* fc2_w = (const float*)d_in[11];
    const float* fc2_b = (const float*)d_in[12];
    float* out = (float*)d_out;

    float* ws = (float*)d_ws;
    float* hbuf   = ws;                       // 33,554,432  (single in-place activation buffer)
    float* tz     = hbuf + 33554432;          // 5,242,880   (stage-A T / stage-C Z share)
    float* xf     = tz + 5242880;             // 819,200
    float* yf     = xf + 819200;              // 819,200
    float* costab = yf + 819200;              // 256
    float* sintab = costab + 256;             // 256
    float* EA     = sintab + 256;             // 10,240
    float* Tw     = EA + 10240;               // 10,240
    float* cwT    = Tw + 10240;               // 16,384
    float* stats  = cwT + 16384;              // 512   (4 layers x [sum64|sumsq64])
    // total: 40,473,608 floats = ~162 MB

    init_k<<<147, 256, 0, stream>>>(cw, costab, sintab, EA, Tw, cwT, stats);
    fc0_k<<<2048, 256, 0, stream>>>(x, fc0_w, fc0_b, hbuf);

    for (int l = 0; l < 4; ++l) {
        dftw_k<<<2048, 128, 0, stream>>>(hbuf, EA, tz);
        dfth_k<<<512, 256, 0, stream>>>(tz, costab, sintab, xf);
        eins_k<<<800, 512, 0, stream>>>(xf, sw1 + l * 3276800, sw2 + l * 3276800, yf);
        idfth_k<<<512, 256, 0, stream>>>(yf, costab, sintab, tz);
        speclin_k<<<2048, 256, 0, stream>>>(hbuf, tz, cwT + l * 4096, Tw, cb + l * 64,
                                            hbuf, stats + l * 128);
        bn_k<<<32768, 256, 0, stream>>>(hbuf, stats + l * 128, bng + l * 64, bnb + l * 64,
                                        (l < 3) ? 1 : 0);
    }
    fc12_k<<<2048, 256, 0, stream>>>(hbuf, fc1_w, fc1_b, fc2_w, fc2_b, out);
}